// Round 1
// baseline (833.337 us; speedup 1.0000x reference)
//
#include <hip/hip_runtime.h>

// Problem constants (fixed by the reference).
#define N_AGENTS 32768
#define FEAT_DIM 64
#define N_FRAMES 64

// out[n, d, t] = mean over d' of in[n, d', t], broadcast across d.
// Layout: in[n][d][t] contiguous, so per-agent tile = 64x64 floats = 1024 float4.
// Thread (n, cg): cg indexes a group of 4 consecutive frames (16 groups of 4).
// Each thread: sum 64 rows (stride 16 float4), scale, write to all 64 rows.
__global__ __launch_bounds__(256) void mean_bcast_kernel(const float4* __restrict__ in4,
                                                         float4* __restrict__ out4) {
    const int gid = blockIdx.x * blockDim.x + threadIdx.x;  // [0, N_AGENTS*16)
    const int n   = gid >> 4;
    const int cg  = gid & 15;
    const size_t base = (size_t)n * (FEAT_DIM * N_FRAMES / 4) + cg;  // float4 units

    float4 acc = make_float4(0.f, 0.f, 0.f, 0.f);
    // 64 row loads; unroll by 16 -> 16 float4 (64 VGPRs) in flight, no spill risk.
    #pragma unroll 16
    for (int d = 0; d < FEAT_DIM; ++d) {
        float4 v = in4[base + (size_t)d * (N_FRAMES / 4)];
        acc.x += v.x;
        acc.y += v.y;
        acc.z += v.z;
        acc.w += v.w;
    }

    const float s = 1.0f / (float)FEAT_DIM;
    const float4 m = make_float4(acc.x * s, acc.y * s, acc.z * s, acc.w * s);

    #pragma unroll 16
    for (int d = 0; d < FEAT_DIM; ++d) {
        out4[base + (size_t)d * (N_FRAMES / 4)] = m;
    }
}

extern "C" void kernel_launch(void* const* d_in, const int* in_sizes, int n_in,
                              void* d_out, int out_size, void* d_ws, size_t ws_size,
                              hipStream_t stream) {
    (void)in_sizes; (void)n_in; (void)d_ws; (void)ws_size; (void)out_size;
    // d_in[0]: in_features fp32 [32768, 64, 64]; d_in[1]: seq_start_end (unused — math is per-agent).
    const float4* in4 = (const float4*)d_in[0];
    float4* out4      = (float4*)d_out;

    const int total_threads = N_AGENTS * (N_FRAMES / 4);  // 524288
    const int block = 256;
    const int grid  = total_threads / block;              // 2048
    mean_bcast_kernel<<<grid, block, 0, stream>>>(in4, out4);
}